// Round 1
// baseline (412.164 us; speedup 1.0000x reference)
//
#include <hip/hip_runtime.h>

typedef _Float16 half8 __attribute__((ext_vector_type(8)));
typedef float f32x4 __attribute__((ext_vector_type(4)));
typedef float f32x16 __attribute__((ext_vector_type(16)));

union H8 { half8 h; float4 f; };

#define EDIM 128
#define CDIM 128
#define HDIM 100
#define ODIM 104

// workspace offsets (bytes), all 256-aligned; total = 14,102,528 bytes
#define OFF_WFRAG  0u          // W_lin B-frags (16x16x32):   8*4*64*8*2  = 32768
#define OFF_WIH    32768u      // wih B-frags (32x32x16):  2*12*8*64*8*2  = 196608
#define OFF_WHH    229376u     // whh B-frags (16x16x32):  2*21*4*64*8*2  = 172032
#define OFF_BIASP  401408u     // gi bias (bih + bhh_{r,z}): 2*384*4      = 3072
#define OFF_BHHN   404480u     // bhh_n padded:              2*128*4      = 1024
#define OFF_STMT   405504u     // stmt f16:                  4096*128*2   = 1048576
#define OFF_GI     1454080u    // gi fp32: 2*64*64*384*4                  = 12582912
#define OFF_POOL   14036992u   // pooled fp32: 2*64*128*4                 = 65536

__device__ inline f32x4 zero4() { f32x4 z = {0.f, 0.f, 0.f, 0.f}; return z; }
__device__ inline float sigmoidf_fast(float x) {
  return __fdividef(1.f, 1.f + __expf(-x));
}
__device__ inline float tanhf_fast(float x) {
  float e2 = __expf(2.f * x);
  return 1.f - __fdividef(2.f, e2 + 1.f);
}

// ---------------------------------------------------------------------------
// K0: convert weights to f16 MFMA fragment layouts + fold biases (runs every call)
// ---------------------------------------------------------------------------
__global__ __launch_bounds__(256) void astnn_prep(
    const float* __restrict__ W_lin,
    const float* __restrict__ wihf, const float* __restrict__ whhf,
    const float* __restrict__ bihf, const float* __restrict__ bhhf,
    const float* __restrict__ wihb, const float* __restrict__ whhb,
    const float* __restrict__ bihb, const float* __restrict__ bhhb,
    _Float16* __restrict__ wfrag, _Float16* __restrict__ wihfrag,
    _Float16* __restrict__ whhfrag, float* __restrict__ biasP,
    float* __restrict__ bhhnP)
{
  int gid = blockIdx.x * 256 + threadIdx.x;
  if (gid < 2048) {
    // W_lin -> 16x16x32 B-frags: B[k][n], lane l: n=l&15, k=kc*32+((l>>4)<<3)+e
    int i = gid, l = i & 63, kc = (i >> 6) & 3, nt = i >> 8;
    int n = (nt << 4) + (l & 15);
    int kb = (kc << 5) + ((l >> 4) << 3);
#pragma unroll
    for (int e = 0; e < 8; e++)
      wfrag[i * 8 + e] = (_Float16)W_lin[(kb + e) * CDIM + n];
  } else if (gid < 14336) {
    // wih -> 32x32x16 B-frags: lane l: n=l&31, k=kc*16+((l>>5)<<3)+e
    // N padded per-section to 128 (3*128=384, 12 tiles of 32)
    int i = gid - 2048, l = i & 63, kc = (i >> 6) & 7;
    int rest = i >> 9, nt = rest % 12, d = rest / 12;
    const float* wih = d ? wihb : wihf;
    int n = (nt << 5) + (l & 31), s = n >> 7, j = n & 127;
    int kb = (kc << 4) + ((l >> 5) << 3);
#pragma unroll
    for (int e = 0; e < 8; e++) {
      float v = (j < HDIM) ? wih[(s * HDIM + j) * CDIM + (kb + e)] : 0.f;
      wihfrag[i * 8 + e] = (_Float16)v;
    }
  } else if (gid < 25088) {
    // whh -> 16x16x32 B-frags: lane l: n=l&15, k=kc*32+((l>>4)<<3)+e
    // N padded per-section to 112 (3*112=336, 21 tiles of 16), K padded to 128
    int i = gid - 14336, l = i & 63, kc = (i >> 6) & 3;
    int rest = i >> 8, nt = rest % 21, d = rest / 21;
    const float* whh = d ? whhb : whhf;
    int n = (nt << 4) + (l & 15), s = n / 112, j = n - 112 * s;
    int kb = (kc << 5) + ((l >> 4) << 3);
#pragma unroll
    for (int e = 0; e < 8; e++) {
      int k = kb + e;
      float v = (j < HDIM && k < HDIM) ? whh[(s * HDIM + j) * HDIM + k] : 0.f;
      whhfrag[i * 8 + e] = (_Float16)v;
    }
  } else if (gid < 25856) {
    // biasP[d][384] = bih[g] + (s<2 ? bhh[g] : 0), pad = 0
    int i = gid - 25088, d = i / 384, col = i % 384, s = col >> 7, j = col & 127;
    const float* bih = d ? bihb : bihf;
    const float* bhh = d ? bhhb : bhhf;
    float v = 0.f;
    if (j < HDIM) { v = bih[s * HDIM + j]; if (s < 2) v += bhh[s * HDIM + j]; }
    biasP[i] = v;
  } else if (gid < 26112) {
    // bhhnP[d][128] = bhh[200+j]
    int i = gid - 25856, d = i / 128, j = i & 127;
    const float* bhh = d ? bhhb : bhhf;
    bhhnP[i] = (j < HDIM) ? bhh[2 * HDIM + j] : 0.f;
  }
}

// ---------------------------------------------------------------------------
// K1: per-block 4 trees (128 nodes): gather emb -> f16 LDS, MFMA x W_lin (+b),
//     subtree-sum via ancestor-bitmask MFMA, max-pool -> stmt (f16)
// ---------------------------------------------------------------------------
__global__ __launch_bounds__(256, 2) void astnn_tree(
    const int* __restrict__ node_ids, const int* __restrict__ parent,
    const float* __restrict__ emb, const float* __restrict__ b_lin,
    const _Float16* __restrict__ wfrag, _Float16* __restrict__ stmt)
{
  __shared__ _Float16 ldsW[16384];   // 32KB: W B-frags (linear frag order)
  __shared__ _Float16 ldsA[16384];   // 32KB: emb tile (swizzled), reused for h-frags
  __shared__ int ldsPar[128];
  __shared__ unsigned ldsAnc[128];

  const int t = threadIdx.x, blk = blockIdx.x;
  const int w = t >> 6, l = t & 63;
  const int base = blk * 128;

  if (t < 128) ldsPar[t] = parent[base + t] & 31;  // trees are 32-aligned globally

  {  // stage W fragments (32KB linear copy)
    const float4* wsrc = (const float4*)wfrag;
#pragma unroll
    for (int i = 0; i < 8; i++) ((float4*)ldsW)[i * 256 + t] = wsrc[i * 256 + t];
  }

  {  // gather embedding rows -> f16, swizzled row-major [128][128]
    const int r = t >> 1, hf = t & 1;
    const int nid = node_ids[base + r];
    const float4* erow = (const float4*)(emb + (size_t)nid * EDIM) + hf * 16;
#pragma unroll
    for (int b2 = 0; b2 < 2; b2++) {
      float4 stage[8];
#pragma unroll
      for (int i = 0; i < 8; i++) stage[i] = erow[b2 * 8 + i];
#pragma unroll
      for (int c4 = 0; c4 < 4; c4++) {
        H8 u;
#pragma unroll
        for (int e = 0; e < 8; e++)
          u.h[e] = (_Float16)(((const float*)&stage[0])[c4 * 8 + e]);
        int c = b2 * 4 + c4;
        int addr = (r * 256 + hf * 128 + c * 16) ^ ((r & 7) << 4);
        *(float4*)((char*)ldsA + addr) = u.f;
      }
    }
  }
  __syncthreads();

  // ancestor-mask build: A[n] = ancestors-or-self bitmask (chain walk, depth<=10)
  if (t < 128) {
    int tree = t >> 5;
    unsigned mask = 0;
    int cur = t & 31;
#pragma unroll
    for (int it = 0; it < 11; ++it) { mask |= (1u << cur); cur = ldsPar[tree * 32 + cur]; }
    ldsAnc[t] = mask;
  }
  __syncthreads();

  // GEMM: h[128][128] = emb_tile @ W  (16x16x32 f16), wave w owns M-tiles 2w,2w+1
  f32x4 acc[2][8];
#pragma unroll
  for (int mt = 0; mt < 2; mt++)
#pragma unroll
    for (int nt = 0; nt < 8; nt++) acc[mt][nt] = zero4();
#pragma unroll
  for (int kc = 0; kc < 4; kc++) {
    half8 af[2];
#pragma unroll
    for (int mt = 0; mt < 2; mt++) {
      int row = (w * 2 + mt) * 16 + (l & 15);
      int addr = (row * 256 + (kc << 6) + ((l >> 4) << 4)) ^ ((row & 7) << 4);
      af[mt] = *(const half8*)((const char*)ldsA + addr);
    }
#pragma unroll
    for (int nt = 0; nt < 8; nt++) {
      half8 bf = *(const half8*)&ldsW[(((nt << 2) | kc) * 64 + l) * 8];
      acc[0][nt] = __builtin_amdgcn_mfma_f32_16x16x32_f16(af[0], bf, acc[0][nt], 0, 0, 0);
      acc[1][nt] = __builtin_amdgcn_mfma_f32_16x16x32_f16(af[1], bf, acc[1][nt], 0, 0, 0);
    }
  }
  __syncthreads();  // all emb-tile reads done; ldsA reused for h-fragments

  // write h (+b_lin) into 32x32x16 B-frag layout: [tree][nt2][kc2][lane][8] f16
#pragma unroll
  for (int mt = 0; mt < 2; mt++) {
    const int Mt = w * 2 + mt, tree = Mt >> 1, kc2 = Mt & 1;
#pragma unroll
    for (int nt = 0; nt < 8; nt++) {
      const float bl = b_lin[nt * 16 + (l & 15)];
      const int nt2 = nt >> 1;
      const int ncol = ((nt & 1) << 4) + (l & 15);
#pragma unroll
      for (int reg = 0; reg < 4; reg++) {
        int rowrem = ((l >> 4) << 2) + reg;          // row within 16x16 C tile
        int l2 = ((rowrem >> 3) << 5) + ncol;
        int idx = (((((tree << 2) + nt2) << 1) + kc2) * 64 + l2) * 8 + (rowrem & 7);
        ldsA[idx] = (_Float16)(acc[mt][nt][reg] + bl);
      }
    }
  }
  __syncthreads();

  // per-tree subtree-sum: S[32][128] = anc(0/1) @ h  (32x32x16), wave w = tree w
  {
    const int tree = w;
    half8 ancf[2];
#pragma unroll
    for (int kc2 = 0; kc2 < 2; kc2++) {
      H8 u;
#pragma unroll
      for (int e = 0; e < 8; e++) {
        int n = (kc2 << 4) + ((l >> 5) << 3) + e;
        unsigned m = ldsAnc[(tree << 5) + n];
        u.h[e] = (_Float16)(float)((m >> (l & 31)) & 1u);
      }
      ancf[kc2] = u.h;
    }
    f32x16 acc2[4];
#pragma unroll
    for (int nt2 = 0; nt2 < 4; nt2++)
#pragma unroll
      for (int e = 0; e < 16; e++) acc2[nt2][e] = 0.f;
#pragma unroll
    for (int nt2 = 0; nt2 < 4; nt2++)
#pragma unroll
      for (int kc2 = 0; kc2 < 2; kc2++) {
        half8 bf = *(const half8*)&ldsA[(((((tree << 2) + nt2) << 1) + kc2) * 64 + l) * 8];
        acc2[nt2] = __builtin_amdgcn_mfma_f32_32x32x16_f16(ancf[kc2], bf, acc2[nt2], 0, 0, 0);
      }
    // max-pool over the 32 node rows -> stmt[tree][c]
#pragma unroll
    for (int nt2 = 0; nt2 < 4; nt2++) {
      float m1 = acc2[nt2][0];
#pragma unroll
      for (int e = 1; e < 16; e++) m1 = fmaxf(m1, acc2[nt2][e]);
      m1 = fmaxf(m1, __shfl_xor(m1, 32));
      if (l < 32)
        stmt[(size_t)(blk * 4 + tree) * CDIM + (nt2 << 5) + l] = (_Float16)m1;
    }
  }
}

// ---------------------------------------------------------------------------
// K2: gi[dir][l][b][384] = stmt @ wih^T + (bih + bhh_{r,z})   (32x32x16 f16)
// ---------------------------------------------------------------------------
__global__ __launch_bounds__(256) void astnn_gi(
    const _Float16* __restrict__ stmt, const _Float16* __restrict__ wihfrag,
    const float* __restrict__ biasP, float* __restrict__ gi)
{
  __shared__ _Float16 ldsA[8192];  // 64 x 128 f16, swizzled
  const int t = threadIdx.x, w = t >> 6, l = t & 63;
  const int mblk = blockIdx.x, dir = blockIdx.y;

  {
    const float4* src = (const float4*)(stmt + (size_t)mblk * 64 * CDIM);
#pragma unroll
    for (int i = 0; i < 4; i++) {
      int id = i * 256 + t, row = id >> 4, ch = id & 15;
      float4 v = src[id];
      *(float4*)((char*)ldsA + ((row * 256 + ch * 16) ^ ((row & 7) << 4))) = v;
    }
  }
  half8 bfr[3][8];
  {
    const half8* wf = (const half8*)wihfrag + dir * 6144;
#pragma unroll
    for (int i = 0; i < 3; i++) {
      int nt = w * 3 + i;
#pragma unroll
      for (int kc = 0; kc < 8; kc++) bfr[i][kc] = wf[((nt << 3) + kc) * 64 + l];
    }
  }
  __syncthreads();

  f32x16 acc[2][3];
#pragma unroll
  for (int mt = 0; mt < 2; mt++)
#pragma unroll
    for (int i = 0; i < 3; i++)
#pragma unroll
      for (int e = 0; e < 16; e++) acc[mt][i][e] = 0.f;

#pragma unroll
  for (int mt = 0; mt < 2; mt++) {
#pragma unroll
    for (int kc = 0; kc < 8; kc++) {
      int row = (mt << 5) + (l & 31);
      int addr = (row * 256 + (kc << 5) + ((l >> 5) << 4)) ^ ((row & 7) << 4);
      half8 af = *(const half8*)((const char*)ldsA + addr);
#pragma unroll
      for (int i = 0; i < 3; i++)
        acc[mt][i] = __builtin_amdgcn_mfma_f32_32x32x16_f16(af, bfr[i][kc], acc[mt][i], 0, 0, 0);
    }
  }
#pragma unroll
  for (int mt = 0; mt < 2; mt++)
#pragma unroll
    for (int i = 0; i < 3; i++) {
      int col = (w * 3 + i) * 32 + (l & 31);
      float bias = biasP[dir * 384 + col];
#pragma unroll
      for (int reg = 0; reg < 16; reg++) {
        int row = (mt << 5) + ((l >> 5) << 2) + (reg & 3) + ((reg >> 2) << 3);
        int tr = mblk * 64 + row;  // tree = b*64 + l_seq
        gi[((size_t)dir * 4096 + (size_t)(tr & 63) * 64 + (tr >> 6)) * 384 + col] =
            acc[mt][i][reg] + bias;
      }
    }
}

// ---------------------------------------------------------------------------
// K3: bidirectional GRU recurrence; 1 block per direction (8 waves).
//     16x16x32 f16 MFMA; waves 0..6 own gate column-group q (j = 16q+(l&15)).
// ---------------------------------------------------------------------------
__global__ __launch_bounds__(512) void astnn_gru(
    const _Float16* __restrict__ whhfrag, const float* __restrict__ gi,
    const float* __restrict__ bhhnP, float* __restrict__ pooled)
{
  __shared__ _Float16 hlds[8192];  // 64 x 128 f16, swizzled
  const int t = threadIdx.x, w = t >> 6, l = t & 63;
  const int dir = blockIdx.x;
  for (int i = t; i < 1024; i += 512)
    ((float4*)hlds)[i] = make_float4(0.f, 0.f, 0.f, 0.f);

  const int q = w;                       // 0..6 active (wave 7 idles)
  const int j = (q << 4) + (l & 15);
  const bool act = (w < 7);
  const bool jv = act && (j < HDIM);

  half8 bfr[3][4];
  float bhhn = 0.f;
  if (act) {
    const half8* wf = (const half8*)whhfrag + dir * 5376;
#pragma unroll
    for (int s = 0; s < 3; s++)
#pragma unroll
      for (int kc = 0; kc < 4; kc++) bfr[s][kc] = wf[(((s * 7 + q) << 2) + kc) * 64 + l];
    bhhn = bhhnP[(dir << 7) + j];
  }
  float hreg[16], pool[16];
#pragma unroll
  for (int i = 0; i < 16; i++) { hreg[i] = 0.f; pool[i] = -3.0e38f; }

  const float* gbase = gi + (size_t)dir * 4096 * 384;
  __syncthreads();

#pragma unroll 1
  for (int step = 0; step < 64; ++step) {
    const int tt = dir ? 63 - step : step;
    const float* gstep = gbase + (size_t)tt * 64 * 384;
    float gv[3][16];
    f32x4 acc[4][3];
    if (act) {
      // issue gi loads early (hidden under MFMA)
#pragma unroll
      for (int s = 0; s < 3; s++)
#pragma unroll
        for (int mt = 0; mt < 4; mt++)
#pragma unroll
          for (int reg = 0; reg < 4; reg++) {
            int row = (mt << 4) + ((l >> 4) << 2) + reg;
            gv[s][(mt << 2) + reg] = gstep[row * 384 + (s << 7) + j];
          }
#pragma unroll
      for (int mt = 0; mt < 4; mt++)
#pragma unroll
        for (int s = 0; s < 3; s++) acc[mt][s] = zero4();
#pragma unroll
      for (int kc = 0; kc < 4; kc++) {
        half8 af[4];
#pragma unroll
        for (int mt = 0; mt < 4; mt++) {
          int row = (mt << 4) + (l & 15);
          int addr = (row * 256 + (kc << 6) + ((l >> 4) << 4)) ^ ((row & 7) << 4);
          af[mt] = *(const half8*)((const char*)hlds + addr);
        }
#pragma unroll
        for (int mt = 0; mt < 4; mt++)
#pragma unroll
          for (int s = 0; s < 3; s++)
            acc[mt][s] = __builtin_amdgcn_mfma_f32_16x16x32_f16(af[mt], bfr[s][kc], acc[mt][s], 0, 0, 0);
      }
    }
    __syncthreads();  // all h reads complete before overwrite
    if (act) {
#pragma unroll
      for (int mt = 0; mt < 4; mt++) {
#pragma unroll
        for (int reg = 0; reg < 4; reg++) {
          const int i16 = (mt << 2) + reg;
          float r = sigmoidf_fast(gv[0][i16] + acc[mt][0][reg]);
          float z = sigmoidf_fast(gv[1][i16] + acc[mt][1][reg]);
          float n = tanhf_fast(gv[2][i16] + r * (acc[mt][2][reg] + bhhn));
          float hn = n + z * (hreg[i16] - n);
          hreg[i16] = hn;
          pool[i16] = fmaxf(pool[i16], hn);
          if (jv) {
            int row = (mt << 4) + ((l >> 4) << 2) + reg;
            *(_Float16*)((char*)hlds + ((row * 256 + (j << 1)) ^ ((row & 7) << 4))) =
                (_Float16)hn;
          }
        }
      }
    }
    __syncthreads();
  }
  if (jv) {
#pragma unroll
    for (int i16 = 0; i16 < 16; i16++) {
      int row = ((i16 >> 2) << 4) + ((l >> 4) << 2) + (i16 & 3);
      pooled[((size_t)dir << 13) + (row << 7) + j] = pool[i16];
    }
  }
}

// ---------------------------------------------------------------------------
// K4: out[b][o] = [pooled_f | pooled_b] @ fc_w + fc_b
// ---------------------------------------------------------------------------
__global__ __launch_bounds__(128) void astnn_fc(
    const float* __restrict__ pooled, const float* __restrict__ fc_w,
    const float* __restrict__ fc_b, float* __restrict__ out)
{
  __shared__ float p[200];
  const int b = blockIdx.x, t = threadIdx.x;
  for (int i = t; i < 200; i += 128) {
    int d = i / 100, jj = i - d * 100;
    p[i] = pooled[((size_t)d << 13) + (b << 7) + jj];
  }
  __syncthreads();
  if (t < ODIM) {
    float a = fc_b[t];
#pragma unroll 8
    for (int k = 0; k < 200; k++) a = fmaf(p[k], fc_w[k * ODIM + t], a);
    out[b * ODIM + t] = a;
  }
}

// ---------------------------------------------------------------------------
extern "C" void kernel_launch(void* const* d_in, const int* in_sizes, int n_in,
                              void* d_out, int out_size, void* d_ws, size_t ws_size,
                              hipStream_t stream)
{
  const int* node_ids = (const int*)d_in[0];
  const int* parent   = (const int*)d_in[1];
  // d_in[2]=level, d_in[3]=tree_id: unused (decreasing-index order suffices)
  const float* emb    = (const float*)d_in[4];
  const float* W_lin  = (const float*)d_in[5];
  const float* b_lin  = (const float*)d_in[6];
  const float* wihf   = (const float*)d_in[7];
  const float* whhf   = (const float*)d_in[8];
  const float* bihf   = (const float*)d_in[9];
  const float* bhhf   = (const float*)d_in[10];
  const float* wihb   = (const float*)d_in[11];
  const float* whhb   = (const float*)d_in[12];
  const float* bihb   = (const float*)d_in[13];
  const float* bhhb   = (const float*)d_in[14];
  const float* fc_w   = (const float*)d_in[15];
  const float* fc_b   = (const float*)d_in[16];

  char* ws = (char*)d_ws;
  _Float16* wfrag   = (_Float16*)(ws + OFF_WFRAG);
  _Float16* wihfrag = (_Float16*)(ws + OFF_WIH);
  _Float16* whhfrag = (_Float16*)(ws + OFF_WHH);
  float* biasP      = (float*)(ws + OFF_BIASP);
  float* bhhnP      = (float*)(ws + OFF_BHHN);
  _Float16* stmt    = (_Float16*)(ws + OFF_STMT);
  float* gi         = (float*)(ws + OFF_GI);
  float* pooled     = (float*)(ws + OFF_POOL);
  float* out        = (float*)d_out;

  astnn_prep<<<102, 256, 0, stream>>>(W_lin, wihf, whhf, bihf, bhhf,
                                      wihb, whhb, bihb, bhhb,
                                      wfrag, wihfrag, whhfrag, biasP, bhhnP);
  astnn_tree<<<1024, 256, 0, stream>>>(node_ids, parent, emb, b_lin, wfrag, stmt);
  astnn_gi<<<dim3(64, 2), 256, 0, stream>>>(stmt, wihfrag, biasP, gi);
  astnn_gru<<<2, 512, 0, stream>>>(whhfrag, gi, bhhnP, pooled);
  astnn_fc<<<64, 128, 0, stream>>>(pooled, fc_w, fc_b, out);
}

// Round 2
// 120.146 us; speedup vs baseline: 3.4305x; 3.4305x over previous
//
#include <hip/hip_runtime.h>

typedef _Float16 half8 __attribute__((ext_vector_type(8)));
typedef float f32x4 __attribute__((ext_vector_type(4)));
typedef float f32x16 __attribute__((ext_vector_type(16)));

union H8 { half8 h; float4 f; };

#define EDIM 128
#define CDIM 128
#define HDIM 100
#define ODIM 104

// workspace offsets (bytes), all 256-aligned; total = 14,102,528 bytes
#define OFF_WFRAG  0u          // W_lin B-frags (16x16x32):   8*4*64*8*2  = 32768
#define OFF_WIH    32768u      // wih B-frags (32x32x16):  2*12*8*64*8*2  = 196608
#define OFF_WHH    229376u     // whh B-frags (16x16x32):  2*21*4*64*8*2  = 172032
#define OFF_BIASP  401408u     // gi bias (bih + bhh_{r,z}): 2*384*4      = 3072
#define OFF_BHHN   404480u     // bhh_n padded:              2*128*4      = 1024
#define OFF_STMT   405504u     // stmt f16:                  4096*128*2   = 1048576
#define OFF_GI     1454080u    // gi fp32: 2*64*64*384*4                  = 12582912
#define OFF_POOL   14036992u   // pooled fp32: 2*64*128*4                 = 65536

__device__ inline f32x4 zero4() { f32x4 z = {0.f, 0.f, 0.f, 0.f}; return z; }
__device__ inline float sigmoidf_fast(float x) {
  return __fdividef(1.f, 1.f + __expf(-x));
}
__device__ inline float tanhf_fast(float x) {
  float e2 = __expf(2.f * x);
  return 1.f - __fdividef(2.f, e2 + 1.f);
}

// ---------------------------------------------------------------------------
// K0: convert weights to f16 MFMA fragment layouts + fold biases (runs every call)
// ---------------------------------------------------------------------------
__global__ __launch_bounds__(256) void astnn_prep(
    const float* __restrict__ W_lin,
    const float* __restrict__ wihf, const float* __restrict__ whhf,
    const float* __restrict__ bihf, const float* __restrict__ bhhf,
    const float* __restrict__ wihb, const float* __restrict__ whhb,
    const float* __restrict__ bihb, const float* __restrict__ bhhb,
    _Float16* __restrict__ wfrag, _Float16* __restrict__ wihfrag,
    _Float16* __restrict__ whhfrag, float* __restrict__ biasP,
    float* __restrict__ bhhnP)
{
  int gid = blockIdx.x * 256 + threadIdx.x;
  if (gid < 2048) {
    // W_lin -> 16x16x32 B-frags: B[k][n], lane l: n=l&15, k=kc*32+((l>>4)<<3)+e
    int i = gid, l = i & 63, kc = (i >> 6) & 3, nt = i >> 8;
    int n = (nt << 4) + (l & 15);
    int kb = (kc << 5) + ((l >> 4) << 3);
#pragma unroll
    for (int e = 0; e < 8; e++)
      wfrag[i * 8 + e] = (_Float16)W_lin[(kb + e) * CDIM + n];
  } else if (gid < 14336) {
    // wih -> 32x32x16 B-frags: lane l: n=l&31, k=kc*16+((l>>5)<<3)+e
    // N padded per-section to 128 (3*128=384, 12 tiles of 32)
    int i = gid - 2048, l = i & 63, kc = (i >> 6) & 7;
    int rest = i >> 9, nt = rest % 12, d = rest / 12;
    const float* wih = d ? wihb : wihf;
    int n = (nt << 5) + (l & 31), s = n >> 7, j = n & 127;
    int kb = (kc << 4) + ((l >> 5) << 3);
#pragma unroll
    for (int e = 0; e < 8; e++) {
      float v = (j < HDIM) ? wih[(s * HDIM + j) * CDIM + (kb + e)] : 0.f;
      wihfrag[i * 8 + e] = (_Float16)v;
    }
  } else if (gid < 25088) {
    // whh -> 16x16x32 B-frags: lane l: n=l&15, k=kc*32+((l>>4)<<3)+e
    // N padded per-section to 112 (3*112=336, 21 tiles of 16), K padded to 128
    int i = gid - 14336, l = i & 63, kc = (i >> 6) & 3;
    int rest = i >> 8, nt = rest % 21, d = rest / 21;
    const float* whh = d ? whhb : whhf;
    int n = (nt << 4) + (l & 15), s = n / 112, j = n - 112 * s;
    int kb = (kc << 5) + ((l >> 4) << 3);
#pragma unroll
    for (int e = 0; e < 8; e++) {
      int k = kb + e;
      float v = (j < HDIM && k < HDIM) ? whh[(s * HDIM + j) * HDIM + k] : 0.f;
      whhfrag[i * 8 + e] = (_Float16)v;
    }
  } else if (gid < 25856) {
    // biasP[d][384] = bih[g] + (s<2 ? bhh[g] : 0), pad = 0
    int i = gid - 25088, d = i / 384, col = i % 384, s = col >> 7, j = col & 127;
    const float* bih = d ? bihb : bihf;
    const float* bhh = d ? bhhb : bhhf;
    float v = 0.f;
    if (j < HDIM) { v = bih[s * HDIM + j]; if (s < 2) v += bhh[s * HDIM + j]; }
    biasP[i] = v;
  } else if (gid < 26112) {
    // bhhnP[d][128] = bhh[200+j]
    int i = gid - 25856, d = i / 128, j = i & 127;
    const float* bhh = d ? bhhb : bhhf;
    bhhnP[i] = (j < HDIM) ? bhh[2 * HDIM + j] : 0.f;
  }
}

// ---------------------------------------------------------------------------
// K1: per-block 4 trees (128 nodes): gather emb -> f16 LDS, MFMA x W_lin (+b),
//     subtree-sum via ancestor-bitmask MFMA, max-pool -> stmt (f16)
// ---------------------------------------------------------------------------
__global__ __launch_bounds__(256, 2) void astnn_tree(
    const int* __restrict__ node_ids, const int* __restrict__ parent,
    const float* __restrict__ emb, const float* __restrict__ b_lin,
    const _Float16* __restrict__ wfrag, _Float16* __restrict__ stmt)
{
  __shared__ _Float16 ldsW[16384];   // 32KB: W B-frags (linear frag order)
  __shared__ _Float16 ldsA[16384];   // 32KB: emb tile (swizzled), reused for h-frags
  __shared__ int ldsPar[128];
  __shared__ unsigned ldsAnc[128];

  const int t = threadIdx.x, blk = blockIdx.x;
  const int w = t >> 6, l = t & 63;
  const int base = blk * 128;

  if (t < 128) ldsPar[t] = parent[base + t] & 31;  // trees are 32-aligned globally

  {  // stage W fragments (32KB linear copy)
    const float4* wsrc = (const float4*)wfrag;
#pragma unroll
    for (int i = 0; i < 8; i++) ((float4*)ldsW)[i * 256 + t] = wsrc[i * 256 + t];
  }

  {  // gather embedding rows -> f16, swizzled row-major [128][128]
    const int r = t >> 1, hf = t & 1;
    const int nid = node_ids[base + r];
    const float4* erow = (const float4*)(emb + (size_t)nid * EDIM) + hf * 16;
#pragma unroll
    for (int b2 = 0; b2 < 2; b2++) {
      float4 stage[8];
#pragma unroll
      for (int i = 0; i < 8; i++) stage[i] = erow[b2 * 8 + i];
#pragma unroll
      for (int c4 = 0; c4 < 4; c4++) {
        H8 u;
#pragma unroll
        for (int e = 0; e < 8; e++)
          u.h[e] = (_Float16)(((const float*)&stage[0])[c4 * 8 + e]);
        int c = b2 * 4 + c4;
        int addr = (r * 256 + hf * 128 + c * 16) ^ ((r & 7) << 4);
        *(float4*)((char*)ldsA + addr) = u.f;
      }
    }
  }
  __syncthreads();

  // ancestor-mask build: A[n] = ancestors-or-self bitmask (chain walk, depth<=10)
  if (t < 128) {
    int tree = t >> 5;
    unsigned mask = 0;
    int cur = t & 31;
#pragma unroll
    for (int it = 0; it < 11; ++it) { mask |= (1u << cur); cur = ldsPar[tree * 32 + cur]; }
    ldsAnc[t] = mask;
  }
  __syncthreads();

  // GEMM: h[128][128] = emb_tile @ W  (16x16x32 f16), wave w owns M-tiles 2w,2w+1
  f32x4 acc[2][8];
#pragma unroll
  for (int mt = 0; mt < 2; mt++)
#pragma unroll
    for (int nt = 0; nt < 8; nt++) acc[mt][nt] = zero4();
#pragma unroll
  for (int kc = 0; kc < 4; kc++) {
    half8 af[2];
#pragma unroll
    for (int mt = 0; mt < 2; mt++) {
      int row = (w * 2 + mt) * 16 + (l & 15);
      int addr = (row * 256 + (kc << 6) + ((l >> 4) << 4)) ^ ((row & 7) << 4);
      af[mt] = *(const half8*)((const char*)ldsA + addr);
    }
#pragma unroll
    for (int nt = 0; nt < 8; nt++) {
      half8 bf = *(const half8*)&ldsW[(((nt << 2) | kc) * 64 + l) * 8];
      acc[0][nt] = __builtin_amdgcn_mfma_f32_16x16x32_f16(af[0], bf, acc[0][nt], 0, 0, 0);
      acc[1][nt] = __builtin_amdgcn_mfma_f32_16x16x32_f16(af[1], bf, acc[1][nt], 0, 0, 0);
    }
  }
  __syncthreads();  // all emb-tile reads done; ldsA reused for h-fragments

  // write h (+b_lin) into 32x32x16 B-frag layout: [tree][nt2][kc2][lane][8] f16
#pragma unroll
  for (int mt = 0; mt < 2; mt++) {
    const int Mt = w * 2 + mt, tree = Mt >> 1, kc2 = Mt & 1;
#pragma unroll
    for (int nt = 0; nt < 8; nt++) {
      const float bl = b_lin[nt * 16 + (l & 15)];
      const int nt2 = nt >> 1;
      const int ncol = ((nt & 1) << 4) + (l & 15);
#pragma unroll
      for (int reg = 0; reg < 4; reg++) {
        int rowrem = ((l >> 4) << 2) + reg;          // row within 16x16 C tile
        int l2 = ((rowrem >> 3) << 5) + ncol;
        int idx = (((((tree << 2) + nt2) << 1) + kc2) * 64 + l2) * 8 + (rowrem & 7);
        ldsA[idx] = (_Float16)(acc[mt][nt][reg] + bl);
      }
    }
  }
  __syncthreads();

  // per-tree subtree-sum: S[32][128] = anc(0/1) @ h  (32x32x16), wave w = tree w
  {
    const int tree = w;
    half8 ancf[2];
#pragma unroll
    for (int kc2 = 0; kc2 < 2; kc2++) {
      H8 u;
#pragma unroll
      for (int e = 0; e < 8; e++) {
        int n = (kc2 << 4) + ((l >> 5) << 3) + e;
        unsigned m = ldsAnc[(tree << 5) + n];
        u.h[e] = (_Float16)(float)((m >> (l & 31)) & 1u);
      }
      ancf[kc2] = u.h;
    }
    f32x16 acc2[4];
#pragma unroll
    for (int nt2 = 0; nt2 < 4; nt2++)
#pragma unroll
      for (int e = 0; e < 16; e++) acc2[nt2][e] = 0.f;
#pragma unroll
    for (int nt2 = 0; nt2 < 4; nt2++)
#pragma unroll
      for (int kc2 = 0; kc2 < 2; kc2++) {
        half8 bf = *(const half8*)&ldsA[(((((tree << 2) + nt2) << 1) + kc2) * 64 + l) * 8];
        acc2[nt2] = __builtin_amdgcn_mfma_f32_32x32x16_f16(ancf[kc2], bf, acc2[nt2], 0, 0, 0);
      }
    // max-pool over the 32 node rows -> stmt[tree][c]
#pragma unroll
    for (int nt2 = 0; nt2 < 4; nt2++) {
      float m1 = acc2[nt2][0];
#pragma unroll
      for (int e = 1; e < 16; e++) m1 = fmaxf(m1, acc2[nt2][e]);
      m1 = fmaxf(m1, __shfl_xor(m1, 32));
      if (l < 32)
        stmt[(size_t)(blk * 4 + tree) * CDIM + (nt2 << 5) + l] = (_Float16)m1;
    }
  }
}

// ---------------------------------------------------------------------------
// K2: gi[dir][l][b][384] = stmt @ wih^T + (bih + bhh_{r,z})   (32x32x16 f16)
// ---------------------------------------------------------------------------
__global__ __launch_bounds__(256) void astnn_gi(
    const _Float16* __restrict__ stmt, const _Float16* __restrict__ wihfrag,
    const float* __restrict__ biasP, float* __restrict__ gi)
{
  __shared__ _Float16 ldsA[8192];  // 64 x 128 f16, swizzled
  const int t = threadIdx.x, w = t >> 6, l = t & 63;
  const int mblk = blockIdx.x, dir = blockIdx.y;

  {
    const float4* src = (const float4*)(stmt + (size_t)mblk * 64 * CDIM);
#pragma unroll
    for (int i = 0; i < 4; i++) {
      int id = i * 256 + t, row = id >> 4, ch = id & 15;
      float4 v = src[id];
      *(float4*)((char*)ldsA + ((row * 256 + ch * 16) ^ ((row & 7) << 4))) = v;
    }
  }
  half8 bfr[3][8];
  {
    const half8* wf = (const half8*)wihfrag + dir * 6144;
#pragma unroll
    for (int i = 0; i < 3; i++) {
      int nt = w * 3 + i;
#pragma unroll
      for (int kc = 0; kc < 8; kc++) bfr[i][kc] = wf[((nt << 3) + kc) * 64 + l];
    }
  }
  __syncthreads();

  f32x16 acc[2][3];
#pragma unroll
  for (int mt = 0; mt < 2; mt++)
#pragma unroll
    for (int i = 0; i < 3; i++)
#pragma unroll
      for (int e = 0; e < 16; e++) acc[mt][i][e] = 0.f;

#pragma unroll
  for (int mt = 0; mt < 2; mt++) {
#pragma unroll
    for (int kc = 0; kc < 8; kc++) {
      int row = (mt << 5) + (l & 31);
      int addr = (row * 256 + (kc << 5) + ((l >> 5) << 4)) ^ ((row & 7) << 4);
      half8 af = *(const half8*)((const char*)ldsA + addr);
#pragma unroll
      for (int i = 0; i < 3; i++)
        acc[mt][i] = __builtin_amdgcn_mfma_f32_32x32x16_f16(af, bfr[i][kc], acc[mt][i], 0, 0, 0);
    }
  }
#pragma unroll
  for (int mt = 0; mt < 2; mt++)
#pragma unroll
    for (int i = 0; i < 3; i++) {
      int col = (w * 3 + i) * 32 + (l & 31);
      float bias = biasP[dir * 384 + col];
#pragma unroll
      for (int reg = 0; reg < 16; reg++) {
        int row = (mt << 5) + ((l >> 5) << 2) + (reg & 3) + ((reg >> 2) << 3);
        int tr = mblk * 64 + row;  // tree = b*64 + l_seq
        gi[((size_t)dir * 4096 + (size_t)(tr & 63) * 64 + (tr >> 6)) * 384 + col] =
            acc[mt][i][reg] + bias;
      }
    }
}

// ---------------------------------------------------------------------------
// K3: bidirectional GRU recurrence, batch-split: grid (4 batch-tiles, 2 dirs),
//     7 waves/block; wave w owns gate columns j=16w+(l&15); M=16 batch rows.
//     Double-buffered h in LDS (1 barrier/step); next-step gi prefetch.
// ---------------------------------------------------------------------------
__global__ __launch_bounds__(448) void astnn_gru(
    const _Float16* __restrict__ whhfrag, const float* __restrict__ gi,
    const float* __restrict__ bhhnP, float* __restrict__ pooled)
{
  __shared__ _Float16 hlds[4096];  // 2 x (16x128 f16, swizzled) double buffer
  const int t = threadIdx.x, w = t >> 6, l = t & 63;
  const int mb = blockIdx.x, dir = blockIdx.y;
  for (int i = t; i < 512; i += 448)          // zero BOTH buffers (cols>=100 stay 0)
    ((float4*)hlds)[i] = make_float4(0.f, 0.f, 0.f, 0.f);

  const int j = (w << 4) + (l & 15);
  const bool jv = (j < HDIM);
  const int rloc = (l >> 4) << 2;             // local row base: 0,4,8,12
  const int grow = (mb << 4) + rloc;          // global batch row base

  half8 bfr[3][4];
  {
    const half8* wf = (const half8*)whhfrag + dir * 5376;
#pragma unroll
    for (int s = 0; s < 3; s++)
#pragma unroll
      for (int kc = 0; kc < 4; kc++)
        bfr[s][kc] = wf[(((s * 7 + w) << 2) + kc) * 64 + l];
  }
  const float bhhn = bhhnP[(dir << 7) + j];

  float hreg[4], pool[4];
#pragma unroll
  for (int i = 0; i < 4; i++) { hreg[i] = 0.f; pool[i] = -3.0e38f; }

  const float* gbase = gi + (size_t)dir * 4096 * 384;
  float gv[12];
  {
    const int tt0 = dir ? 63 : 0;
#pragma unroll
    for (int s = 0; s < 3; s++)
#pragma unroll
      for (int reg = 0; reg < 4; reg++)
        gv[s * 4 + reg] = gbase[(size_t)(tt0 * 64 + grow + reg) * 384 + (s << 7) + j];
  }
  __syncthreads();

#pragma unroll 1
  for (int step = 0; step < 64; ++step) {
    const int sn = (step + 1 < 64) ? step + 1 : 63;
    const int ttn = dir ? 63 - sn : sn;
    float gvn[12];
#pragma unroll
    for (int s = 0; s < 3; s++)
#pragma unroll
      for (int reg = 0; reg < 4; reg++)
        gvn[s * 4 + reg] = gbase[(size_t)(ttn * 64 + grow + reg) * 384 + (s << 7) + j];

    const int roff = (step & 1) << 12, woff = roff ^ 4096;
    f32x4 acc[3];
    acc[0] = zero4(); acc[1] = zero4(); acc[2] = zero4();
#pragma unroll
    for (int kc = 0; kc < 4; kc++) {
      int row = l & 15;
      int addr = ((row * 256 + (kc << 6) + ((l >> 4) << 4)) ^ ((row & 7) << 4)) + roff;
      half8 af = *(const half8*)((const char*)hlds + addr);
#pragma unroll
      for (int s = 0; s < 3; s++)
        acc[s] = __builtin_amdgcn_mfma_f32_16x16x32_f16(af, bfr[s][kc], acc[s], 0, 0, 0);
    }
#pragma unroll
    for (int reg = 0; reg < 4; reg++) {
      float r = sigmoidf_fast(gv[reg] + acc[0][reg]);
      float z = sigmoidf_fast(gv[4 + reg] + acc[1][reg]);
      float n = tanhf_fast(gv[8 + reg] + r * (acc[2][reg] + bhhn));
      float hn = n + z * (hreg[reg] - n);
      hreg[reg] = hn;
      pool[reg] = fmaxf(pool[reg], hn);
      if (jv) {
        int rw = rloc + reg;
        *(_Float16*)((char*)hlds +
                     (((rw * 256 + (j << 1)) ^ ((rw & 7) << 4)) + woff)) = (_Float16)hn;
      }
    }
    __syncthreads();   // writes to woff visible before next iter reads them
#pragma unroll
    for (int i = 0; i < 12; i++) gv[i] = gvn[i];
  }
  if (jv) {
#pragma unroll
    for (int reg = 0; reg < 4; reg++)
      pooled[((size_t)dir << 13) + ((size_t)(grow + reg) << 7) + j] = pool[reg];
  }
}

// ---------------------------------------------------------------------------
// K4: out[b][o] = [pooled_f | pooled_b] @ fc_w + fc_b
// ---------------------------------------------------------------------------
__global__ __launch_bounds__(128) void astnn_fc(
    const float* __restrict__ pooled, const float* __restrict__ fc_w,
    const float* __restrict__ fc_b, float* __restrict__ out)
{
  __shared__ float p[200];
  const int b = blockIdx.x, t = threadIdx.x;
  for (int i = t; i < 200; i += 128) {
    int d = i / 100, jj = i - d * 100;
    p[i] = pooled[((size_t)d << 13) + (b << 7) + jj];
  }
  __syncthreads();
  if (t < ODIM) {
    float a = fc_b[t];
#pragma unroll 8
    for (int k = 0; k < 200; k++) a = fmaf(p[k], fc_w[k * ODIM + t], a);
    out[b * ODIM + t] = a;
  }
}

// ---------------------------------------------------------------------------
extern "C" void kernel_launch(void* const* d_in, const int* in_sizes, int n_in,
                              void* d_out, int out_size, void* d_ws, size_t ws_size,
                              hipStream_t stream)
{
  const int* node_ids = (const int*)d_in[0];
  const int* parent   = (const int*)d_in[1];
  // d_in[2]=level, d_in[3]=tree_id: unused (decreasing-index order suffices)
  const float* emb    = (const float*)d_in[4];
  const float* W_lin  = (const float*)d_in[5];
  const float* b_lin  = (const float*)d_in[6];
  const float* wihf   = (const float*)d_in[7];
  const float* whhf   = (const float*)d_in[8];
  const float* bihf   = (const float*)d_in[9];
  const float* bhhf   = (const float*)d_in[10];
  const float* wihb   = (const float*)d_in[11];
  const float* whhb   = (const float*)d_in[12];
  const float* bihb   = (const float*)d_in[13];
  const float* bhhb   = (const float*)d_in[14];
  const float* fc_w   = (const float*)d_in[15];
  const float* fc_b   = (const float*)d_in[16];

  char* ws = (char*)d_ws;
  _Float16* wfrag   = (_Float16*)(ws + OFF_WFRAG);
  _Float16* wihfrag = (_Float16*)(ws + OFF_WIH);
  _Float16* whhfrag = (_Float16*)(ws + OFF_WHH);
  float* biasP      = (float*)(ws + OFF_BIASP);
  float* bhhnP      = (float*)(ws + OFF_BHHN);
  _Float16* stmt    = (_Float16*)(ws + OFF_STMT);
  float* gi         = (float*)(ws + OFF_GI);
  float* pooled     = (float*)(ws + OFF_POOL);
  float* out        = (float*)d_out;

  astnn_prep<<<102, 256, 0, stream>>>(W_lin, wihf, whhf, bihf, bhhf,
                                      wihb, whhb, bihb, bhhb,
                                      wfrag, wihfrag, whhfrag, biasP, bhhnP);
  astnn_tree<<<1024, 256, 0, stream>>>(node_ids, parent, emb, b_lin, wfrag, stmt);
  astnn_gi<<<dim3(64, 2), 256, 0, stream>>>(stmt, wihfrag, biasP, gi);
  astnn_gru<<<dim3(4, 2), 448, 0, stream>>>(whhfrag, gi, bhhnP, pooled);
  astnn_fc<<<64, 128, 0, stream>>>(pooled, fc_w, fc_b, out);
}